// Round 1
// baseline (700.561 us; speedup 1.0000x reference)
//
#include <hip/hip_runtime.h>
#include <stdint.h>

typedef unsigned short ushort_t;
typedef __attribute__((ext_vector_type(8))) short bf16x8;   // 8 bf16 = 4 VGPRs
typedef __attribute__((ext_vector_type(4))) float f32x4;

__device__ __forceinline__ ushort_t f2bf(float f) {
  union { float f; uint32_t u; } v; v.f = f;
  uint32_t u = v.u;
  u += 0x7FFFu + ((u >> 16) & 1u);   // RNE
  return (ushort_t)(u >> 16);
}

__device__ __forceinline__ float bf2f(ushort_t h) {
  union { uint32_t u; float f; } v; v.u = ((uint32_t)h) << 16;
  return v.f;
}

// async global->LDS 16B; lds dest is wave-uniform base + lane*16 (our offsets match)
__device__ __forceinline__ void gl2lds16(const void* g, void* l) {
  __builtin_amdgcn_global_load_lds(
      (__attribute__((address_space(1))) void*)(uintptr_t)g,
      (__attribute__((address_space(3))) void*)(uint32_t)(uintptr_t)l,
      16, 0, 0);
}

// C[m][n] = sum_k A[m][k] * Bt[n][k]
// AFP32: A is fp32, converted to bf16 during LDS staging; else A is bf16 (global_load_lds).
// EPI: 0 = bf16 store C[m*N+n]
//      1 = bf16 TRANSPOSED store: C[((b*N + n)*npb) + (m%npb)], b = m/npb  (writes K^T/V^T)
//      2 = like 0 but multiply by bf16 mulsrc[m*N+n] first (query gate)
//      3 = fp32 store C[m*N+n]
// BT_PER_BATCH: Bt += (m0/npb)*N*K  (per-batch KV^T in the final GEMM)
template <bool AFP32, int EPI, bool BT_PER_BATCH>
__global__ __launch_bounds__(256) void gemm_bt(
    const void* __restrict__ Aptr, const ushort_t* __restrict__ Bt,
    void* __restrict__ Cptr, const ushort_t* __restrict__ mulsrc,
    int M, int N, int K, int npb,
    long long aStride, long long btStride, long long cStride) {
  __shared__ ushort_t As[128 * 32];
  __shared__ ushort_t Bs[128 * 32];

  const int t = threadIdx.x;
  const int lane = t & 63;
  const int wid = t >> 6;
  const int wm = wid & 1, wn = wid >> 1;   // 2x2 wave grid, each wave 64x64
  const int lr = lane & 15, lq = lane >> 4;

  const int n0 = blockIdx.x * 128;
  const int m0 = blockIdx.y * 128;
  const int bz = blockIdx.z;

  const ushort_t* btp = Bt + (size_t)bz * btStride;
  if constexpr (BT_PER_BATCH) btp += (size_t)(m0 / npb) * N * K;

  const float* Af = (const float*)Aptr + (size_t)bz * aStride;
  const ushort_t* Ab = (const ushort_t*)Aptr + (size_t)bz * aStride;

  f32x4 acc[4][4] = {};

  const int soff = (wid * 2) * 1024 + lane * 16;  // byte offset, staging chunk base

  for (int k0 = 0; k0 < K; k0 += 32) {
    // ---- stage Bt tile (128 rows x 32 k, bf16, no pad) via global_load_lds x16B
    #pragma unroll
    for (int i = 0; i < 2; ++i) {
      int off = soff + i * 1024;
      int row = off >> 6;            // 64B per row of 32 bf16
      int col = (off & 63) >> 1;
      gl2lds16(btp + (size_t)(n0 + row) * K + (k0 + col), (char*)Bs + off);
    }
    // ---- stage A tile
    if constexpr (AFP32) {
      #pragma unroll
      for (int r = 0; r < 4; ++r) {
        int idx = (r * 256 + t) * 4;       // element index in 128x32 tile
        int row = idx >> 5, col = idx & 31;
        float4 f = *(const float4*)(Af + (size_t)(m0 + row) * K + (k0 + col));
        ushort4 u = make_ushort4(f2bf(f.x), f2bf(f.y), f2bf(f.z), f2bf(f.w));
        *(ushort4*)&As[idx] = u;
      }
    } else {
      #pragma unroll
      for (int i = 0; i < 2; ++i) {
        int off = soff + i * 1024;
        int row = off >> 6;
        int col = (off & 63) >> 1;
        gl2lds16(Ab + (size_t)(m0 + row) * K + (k0 + col), (char*)As + off);
      }
    }
    __syncthreads();

    // ---- MFMA: A-frag A[m=lane&15][k=quad*8+j], B-frag Bt[n=lane&15][k=quad*8+j]
    bf16x8 a[4], b[4];
    #pragma unroll
    for (int mi = 0; mi < 4; ++mi)
      a[mi] = *(const bf16x8*)&As[(wm * 64 + mi * 16 + lr) * 32 + lq * 8];
    #pragma unroll
    for (int ni = 0; ni < 4; ++ni)
      b[ni] = *(const bf16x8*)&Bs[(wn * 64 + ni * 16 + lr) * 32 + lq * 8];
    #pragma unroll
    for (int mi = 0; mi < 4; ++mi)
      #pragma unroll
      for (int ni = 0; ni < 4; ++ni)
        acc[mi][ni] = __builtin_amdgcn_mfma_f32_16x16x32_bf16(a[mi], b[ni], acc[mi][ni], 0, 0, 0);
    __syncthreads();
  }

  // ---- epilogue. C/D layout: col = lane&15, row = quad*4 + reg  (HW-verified)
  if constexpr (EPI == 3) {
    float* C = (float*)Cptr + (size_t)bz * cStride;
    #pragma unroll
    for (int mi = 0; mi < 4; ++mi) {
      int rbase = m0 + wm * 64 + mi * 16 + lq * 4;
      #pragma unroll
      for (int ni = 0; ni < 4; ++ni) {
        int c = n0 + wn * 64 + ni * 16 + lr;
        #pragma unroll
        for (int r = 0; r < 4; ++r)
          C[(size_t)(rbase + r) * N + c] = acc[mi][ni][r];
      }
    }
  } else if constexpr (EPI == 1) {
    ushort_t* C = (ushort_t*)Cptr;
    #pragma unroll
    for (int mi = 0; mi < 4; ++mi) {
      int rbase = m0 + wm * 64 + mi * 16 + lq * 4;
      int b = rbase / npb, nin = rbase % npb;   // 4 regs stay in one batch (npb%4==0)
      #pragma unroll
      for (int ni = 0; ni < 4; ++ni) {
        int c = n0 + wn * 64 + ni * 16 + lr;
        ushort4 u = make_ushort4(f2bf(acc[mi][ni][0]), f2bf(acc[mi][ni][1]),
                                 f2bf(acc[mi][ni][2]), f2bf(acc[mi][ni][3]));
        *(ushort4*)&C[((size_t)b * N + c) * npb + nin] = u;
      }
    }
  } else {
    ushort_t* C = (ushort_t*)Cptr + (size_t)bz * cStride;
    #pragma unroll
    for (int mi = 0; mi < 4; ++mi) {
      int rbase = m0 + wm * 64 + mi * 16 + lq * 4;
      #pragma unroll
      for (int ni = 0; ni < 4; ++ni) {
        int c = n0 + wn * 64 + ni * 16 + lr;
        #pragma unroll
        for (int r = 0; r < 4; ++r) {
          float v = acc[mi][ni][r];
          if constexpr (EPI == 2) v *= bf2f(mulsrc[(size_t)(rbase + r) * N + c]);
          C[(size_t)(rbase + r) * N + c] = f2bf(v);
        }
      }
    }
  }
}

// Wt[e][d] = bf16(W[d][e]), 1024x1024, LDS-tiled transpose
__global__ __launch_bounds__(256) void wtrans(const float* __restrict__ W,
                                              ushort_t* __restrict__ Wt) {
  __shared__ float tile[32][33];
  const int tx = threadIdx.x, ty = threadIdx.y;   // (32, 8)
  const int bx = blockIdx.x * 32, by = blockIdx.y * 32;
  #pragma unroll
  for (int k = 0; k < 32; k += 8)
    tile[ty + k][tx] = W[(size_t)(by + ty + k) * 1024 + bx + tx];
  __syncthreads();
  #pragma unroll
  for (int k = 0; k < 32; k += 8)
    Wt[(size_t)(bx + ty + k) * 1024 + by + tx] = f2bf(tile[tx][ty + k]);
}

extern "C" void kernel_launch(void* const* d_in, const int* in_sizes, int n_in,
                              void* d_out, int out_size, void* d_ws, size_t ws_size,
                              hipStream_t stream) {
  const float* xr  = (const float*)d_in[0];
  const float* xi  = (const float*)d_in[1];
  const float* wqr = (const float*)d_in[2];
  const float* wqi = (const float*)d_in[3];
  const float* wk  = (const float*)d_in[4];
  const float* wv  = (const float*)d_in[5];

  const int B = 4, N = 4096, D = 1024;
  const int M = B * N;             // 16384
  char* ws = (char*)d_ws;
  const size_t MB = 1024ull * 1024ull;
  ushort_t* WtQR = (ushort_t*)(ws + 0 * MB);     // 2MB each
  ushort_t* WtQI = (ushort_t*)(ws + 2 * MB);
  ushort_t* WtK  = (ushort_t*)(ws + 4 * MB);
  ushort_t* WtV  = (ushort_t*)(ws + 6 * MB);
  ushort_t* KT   = (ushort_t*)(ws + 8 * MB);     // [4][1024][4096] bf16 = 32MB
  ushort_t* VT   = (ushort_t*)(ws + 40 * MB);    // 32MB
  ushort_t* Q    = (ushort_t*)(ws + 72 * MB);    // [16384][1024] bf16 = 32MB
  ushort_t* KVT  = (ushort_t*)(ws + 104 * MB);   // [4][1024][1024] bf16 = 8MB
  ushort_t* QR   = (ushort_t*)d_out;             // 32MB scratch inside 64MB d_out

  // 1) weight transpose+convert
  dim3 tb(32, 8), tg(32, 32);
  wtrans<<<tg, tb, 0, stream>>>(wk, WtK);
  wtrans<<<tg, tb, 0, stream>>>(wv, WtV);
  wtrans<<<tg, tb, 0, stream>>>(wqr, WtQR);
  wtrans<<<tg, tb, 0, stream>>>(wqi, WtQI);

  dim3 blk(256);
  // 2) K^T = (Xr @ Wk)^T, V^T = (Xi @ Wv)^T   [b][d][n]
  gemm_bt<true, 1, false><<<dim3(8, 128, 1), blk, 0, stream>>>(
      xr, WtK, KT, nullptr, M, D, D, N, 0, 0, 0);
  gemm_bt<true, 1, false><<<dim3(8, 128, 1), blk, 0, stream>>>(
      xi, WtV, VT, nullptr, M, D, D, N, 0, 0, 0);
  // 3) Qr = Xr @ Wqr (scratch), then Q = Qr * (Xi @ Wqi)
  gemm_bt<true, 0, false><<<dim3(8, 128, 1), blk, 0, stream>>>(
      xr, WtQR, QR, nullptr, M, D, D, N, 0, 0, 0);
  gemm_bt<true, 2, false><<<dim3(8, 128, 1), blk, 0, stream>>>(
      xi, WtQI, Q, QR, M, D, D, N, 0, 0, 0);
  // 4) KV^T[b][e][d] = sum_n V^T[b][e][n] * K^T[b][d][n]   (gemm_bt over K=4096)
  gemm_bt<false, 0, false><<<dim3(8, 8, 4), blk, 0, stream>>>(
      VT, KT, KVT, nullptr, D, D, N, N,
      (long long)D * N, (long long)D * N, (long long)D * D);
  // 5) Out[n][e] = sum_d Q[n][d] * KV^T[b(e-row)][e][d]  -> fp32 d_out
  gemm_bt<false, 3, true><<<dim3(8, 128, 1), blk, 0, stream>>>(
      Q, KVT, d_out, nullptr, M, D, D, N, 0, 0, 0);
}

// Round 2
// 505.202 us; speedup vs baseline: 1.3867x; 1.3867x over previous
//
#include <hip/hip_runtime.h>
#include <stdint.h>

typedef unsigned short ushort_t;
typedef __attribute__((ext_vector_type(8))) short bf16x8;   // 8 bf16 = 4 VGPRs
typedef __attribute__((ext_vector_type(4))) float f32x4;

__device__ __forceinline__ ushort_t f2bf(float f) {
  union { float f; uint32_t u; } v; v.f = f;
  uint32_t u = v.u;
  u += 0x7FFFu + ((u >> 16) & 1u);   // RNE
  return (ushort_t)(u >> 16);
}
__device__ __forceinline__ float bf2f(ushort_t h) {
  union { uint32_t u; float f; } v; v.u = ((uint32_t)h) << 16;
  return v.f;
}
__device__ __forceinline__ void gl2lds16(const void* g, void* l) {
  __builtin_amdgcn_global_load_lds(
      (__attribute__((address_space(1))) void*)(uintptr_t)g,
      (__attribute__((address_space(3))) void*)(uint32_t)(uintptr_t)l,
      16, 0, 0);
}

// ---- shared 128x128-tile bf16 GEMM main loop (C = A * Bt^T), swizzled LDS ----
// LDS slot for logical (row, kg): kg' = kg ^ ((row>>1)&3). Staging picks the
// per-lane GLOBAL source so slot L receives the right element; fragment reads
// apply the same XOR -> bank-balanced (2-way max) ds_read_b128.
__device__ __forceinline__ void gemm_loop(
    const ushort_t* __restrict__ A, int lda,
    const ushort_t* __restrict__ Bt, int ldb,
    int m0, int n0, int K,
    ushort_t* __restrict__ As, ushort_t* __restrict__ Bs,
    f32x4 (&acc)[4][4]) {
  const int t = threadIdx.x;
  const int lane = t & 63, wid = t >> 6;
  const int wm = wid & 1, wn = wid >> 1;
  const int lr = lane & 15, lq = lane >> 4;

  // staging: slot s' = wid*128 + i*64 + lane ; row = s'>>2 ; kg = (s'&3)^((row>>1)&3)
  const int row0 = wid * 32 + (lane >> 2);
  const int row1 = row0 + 16;
  const int kg0 = (lane & 3) ^ ((row0 >> 1) & 3);
  const int kg1 = (lane & 3) ^ ((row1 >> 1) & 3);
  const int dst0 = (wid * 128 + lane) * 16;
  const int dst1 = dst0 + 1024;

  const ushort_t* ap0 = A + (size_t)(m0 + row0) * lda + kg0 * 8;
  const ushort_t* ap1 = A + (size_t)(m0 + row1) * lda + kg1 * 8;
  const ushort_t* bp0 = Bt + (size_t)(n0 + row0) * ldb + kg0 * 8;
  const ushort_t* bp1 = Bt + (size_t)(n0 + row1) * ldb + kg1 * 8;

  const int swz = (lq ^ ((lr >> 1) & 3)) * 16;
  int aoff[4], boff[4];
  #pragma unroll
  for (int i = 0; i < 4; ++i) {
    aoff[i] = (wm * 64 + i * 16 + lr) * 64 + swz;
    boff[i] = (wn * 64 + i * 16 + lr) * 64 + swz;
  }

  for (int k0 = 0; k0 < K; k0 += 32) {
    gl2lds16(bp0 + k0, (char*)Bs + dst0);
    gl2lds16(bp1 + k0, (char*)Bs + dst1);
    gl2lds16(ap0 + k0, (char*)As + dst0);
    gl2lds16(ap1 + k0, (char*)As + dst1);
    __syncthreads();
    bf16x8 af[4], bfr[4];
    #pragma unroll
    for (int i = 0; i < 4; ++i) af[i] = *(const bf16x8*)((const char*)As + aoff[i]);
    #pragma unroll
    for (int i = 0; i < 4; ++i) bfr[i] = *(const bf16x8*)((const char*)Bs + boff[i]);
    #pragma unroll
    for (int mi = 0; mi < 4; ++mi)
      #pragma unroll
      for (int ni = 0; ni < 4; ++ni)
        acc[mi][ni] = __builtin_amdgcn_mfma_f32_16x16x32_bf16(af[mi], bfr[ni], acc[mi][ni], 0, 0, 0);
    __syncthreads();
  }
}

// ---- fused projection: X[16384][1024] @ Wt[2048][1024]^T ----
// n0 < 1024  -> Cq[m][c] bf16 (GATE: multiplied by gate[m][c])
// n0 >= 1024 -> transposed store Ct[b][d][nseq] bf16, d = c-1024
template <bool GATE>
__global__ __launch_bounds__(256) void proj_gemm(
    const ushort_t* __restrict__ X, const ushort_t* __restrict__ Wt,
    ushort_t* __restrict__ Cq, ushort_t* __restrict__ Ct,
    const ushort_t* __restrict__ gate) {
  __shared__ ushort_t As[128 * 32];
  __shared__ ushort_t Bs[128 * 32];
  const int n0 = blockIdx.x * 128, m0 = blockIdx.y * 128;
  f32x4 acc[4][4] = {};
  gemm_loop(X, 1024, Wt, 1024, m0, n0, 1024, As, Bs, acc);

  const int t = threadIdx.x, lane = t & 63, wid = t >> 6;
  const int wm = wid & 1, wn = wid >> 1;
  const int lr = lane & 15, lq = lane >> 4;

  if (n0 < 1024) {
    #pragma unroll
    for (int mi = 0; mi < 4; ++mi) {
      int rbase = m0 + wm * 64 + mi * 16 + lq * 4;
      #pragma unroll
      for (int ni = 0; ni < 4; ++ni) {
        int c = n0 + wn * 64 + ni * 16 + lr;
        #pragma unroll
        for (int r = 0; r < 4; ++r) {
          float v = acc[mi][ni][r];
          if constexpr (GATE) v *= bf2f(gate[(size_t)(rbase + r) * 1024 + c]);
          Cq[(size_t)(rbase + r) * 1024 + c] = f2bf(v);
        }
      }
    }
  } else {
    #pragma unroll
    for (int mi = 0; mi < 4; ++mi) {
      int m = m0 + wm * 64 + mi * 16 + lq * 4;
      int b = m >> 12, nseq = m & 4095;
      #pragma unroll
      for (int ni = 0; ni < 4; ++ni) {
        int d = n0 - 1024 + wn * 64 + ni * 16 + lr;
        ushort4 u = make_ushort4(f2bf(acc[mi][ni][0]), f2bf(acc[mi][ni][1]),
                                 f2bf(acc[mi][ni][2]), f2bf(acc[mi][ni][3]));
        *(ushort4*)&Ct[((size_t)(b * 1024 + d) << 12) + nseq] = u;
      }
    }
  }
}

// ---- split-K KV: partial[z][e][d] = sum_{n in chunk s} V^T[b][e][n]*K^T[b][d][n], z=s*4+b
__global__ __launch_bounds__(256) void kv_gemm(
    const ushort_t* __restrict__ VT, const ushort_t* __restrict__ KT,
    float* __restrict__ P) {
  __shared__ ushort_t As[128 * 32];
  __shared__ ushort_t Bs[128 * 32];
  const int z = blockIdx.z, b = z & 3, s = z >> 2;
  const int n0 = blockIdx.x * 128, m0 = blockIdx.y * 128;
  const ushort_t* A = VT + ((size_t)b << 22) + s * 1024;   // b*1024*4096
  const ushort_t* Bt = KT + ((size_t)b << 22) + s * 1024;
  f32x4 acc[4][4] = {};
  gemm_loop(A, 4096, Bt, 4096, m0, n0, 1024, As, Bs, acc);

  const int t = threadIdx.x, lane = t & 63, wid = t >> 6;
  const int wm = wid & 1, wn = wid >> 1;
  const int lr = lane & 15, lq = lane >> 4;
  float* C = P + ((size_t)z << 20);
  #pragma unroll
  for (int mi = 0; mi < 4; ++mi) {
    int rbase = m0 + wm * 64 + mi * 16 + lq * 4;
    #pragma unroll
    for (int ni = 0; ni < 4; ++ni) {
      int c = n0 + wn * 64 + ni * 16 + lr;
      #pragma unroll
      for (int r = 0; r < 4; ++r)
        C[(size_t)(rbase + r) * 1024 + c] = acc[mi][ni][r];
    }
  }
}

__global__ __launch_bounds__(256) void kv_reduce(const float* __restrict__ P,
                                                 ushort_t* __restrict__ KVT) {
  size_t e4 = ((size_t)blockIdx.x * 256 + threadIdx.x) * 4;  // < 4M
  int b = (int)(e4 >> 20);
  size_t j = e4 & ((1u << 20) - 1);
  float4 s = make_float4(0.f, 0.f, 0.f, 0.f);
  #pragma unroll
  for (int sp = 0; sp < 4; ++sp) {
    float4 v = *(const float4*)(P + ((size_t)(sp * 4 + b) << 20) + j);
    s.x += v.x; s.y += v.y; s.z += v.z; s.w += v.w;
  }
  *(ushort4*)&KVT[e4] = make_ushort4(f2bf(s.x), f2bf(s.y), f2bf(s.z), f2bf(s.w));
}

// ---- final: Out[m][e] = sum_d Q[m][d] * KVT[b(m)][e][d], fp32 out ----
__global__ __launch_bounds__(256) void fin_gemm(
    const ushort_t* __restrict__ Q, const ushort_t* __restrict__ KVT,
    float* __restrict__ Out) {
  __shared__ ushort_t As[128 * 32];
  __shared__ ushort_t Bs[128 * 32];
  const int n0 = blockIdx.x * 128, m0 = blockIdx.y * 128;
  const int b = m0 >> 12;
  f32x4 acc[4][4] = {};
  gemm_loop(Q, 1024, KVT + ((size_t)b << 20), 1024, m0, n0, 1024, As, Bs, acc);

  const int t = threadIdx.x, lane = t & 63, wid = t >> 6;
  const int wm = wid & 1, wn = wid >> 1;
  const int lr = lane & 15, lq = lane >> 4;
  #pragma unroll
  for (int mi = 0; mi < 4; ++mi) {
    int rbase = m0 + wm * 64 + mi * 16 + lq * 4;
    #pragma unroll
    for (int ni = 0; ni < 4; ++ni) {
      int c = n0 + wn * 64 + ni * 16 + lr;
      #pragma unroll
      for (int r = 0; r < 4; ++r)
        Out[(size_t)(rbase + r) * 1024 + c] = acc[mi][ni][r];
    }
  }
}

// ---- weight transpose+convert, all four in one launch (z selects) ----
__global__ __launch_bounds__(256) void wtrans4(
    const float* w0, const float* w1, const float* w2, const float* w3,
    ushort_t* o0, ushort_t* o1, ushort_t* o2, ushort_t* o3) {
  __shared__ float tile[32][33];
  const float* W; ushort_t* O;
  switch (blockIdx.z) {
    case 0: W = w0; O = o0; break;
    case 1: W = w1; O = o1; break;
    case 2: W = w2; O = o2; break;
    default: W = w3; O = o3; break;
  }
  const int tx = threadIdx.x, ty = threadIdx.y;   // (32, 8)
  const int bx = blockIdx.x * 32, by = blockIdx.y * 32;
  #pragma unroll
  for (int k = 0; k < 32; k += 8)
    tile[ty + k][tx] = W[(size_t)(by + ty + k) * 1024 + bx + tx];
  __syncthreads();
  #pragma unroll
  for (int k = 0; k < 32; k += 8)
    O[(size_t)(bx + ty + k) * 1024 + by + tx] = f2bf(tile[tx][ty + k]);
}

// ---- X fp32 -> bf16, both tensors in one launch ----
__global__ __launch_bounds__(256) void xconvert(
    const float* __restrict__ xr, const float* __restrict__ xi,
    ushort_t* __restrict__ xrb, ushort_t* __restrict__ xib) {
  const size_t T = 16u * 1024u * 1024u;
  size_t e = ((size_t)blockIdx.x * 256 + threadIdx.x) * 8;
  const float* src; ushort_t* dst;
  if (e < T) { src = xr + e; dst = xrb + e; }
  else       { src = xi + (e - T); dst = xib + (e - T); }
  float4 f0 = *(const float4*)src;
  float4 f1 = *(const float4*)(src + 4);
  ushort4 u0 = make_ushort4(f2bf(f0.x), f2bf(f0.y), f2bf(f0.z), f2bf(f0.w));
  ushort4 u1 = make_ushort4(f2bf(f1.x), f2bf(f1.y), f2bf(f1.z), f2bf(f1.w));
  *(ushort4*)dst = u0;
  *(ushort4*)(dst + 4) = u1;
}

extern "C" void kernel_launch(void* const* d_in, const int* in_sizes, int n_in,
                              void* d_out, int out_size, void* d_ws, size_t ws_size,
                              hipStream_t stream) {
  const float* xr  = (const float*)d_in[0];
  const float* xi  = (const float*)d_in[1];
  const float* wqr = (const float*)d_in[2];
  const float* wqi = (const float*)d_in[3];
  const float* wk  = (const float*)d_in[4];
  const float* wv  = (const float*)d_in[5];

  char* ws = (char*)d_ws;
  const size_t MB = 1024ull * 1024ull;
  // ws layout (136 MB), with overlays:
  ushort_t* WtQR = (ushort_t*)(ws + 0 * MB);    // [WtQR;WtK] = contiguous [2048][1024]
  ushort_t* WtK  = (ushort_t*)(ws + 2 * MB);
  ushort_t* WtQI = (ushort_t*)(ws + 4 * MB);    // [WtQI;WtV] contiguous
  ushort_t* WtV  = (ushort_t*)(ws + 6 * MB);
  ushort_t* Xrb  = (ushort_t*)(ws + 8 * MB);    // 32MB; dead after proj1 -> VT overlays
  ushort_t* Xib  = (ushort_t*)(ws + 40 * MB);   // 32MB; dead after proj2 -> KVT overlays
  ushort_t* KT   = (ushort_t*)(ws + 72 * MB);   // 32MB [4][1024][4096]
  ushort_t* Q    = (ushort_t*)(ws + 104 * MB);  // 32MB
  ushort_t* VT   = (ushort_t*)(ws + 8 * MB);    // overlay on Xrb
  ushort_t* KVT  = (ushort_t*)(ws + 40 * MB);   // overlay on Xib, 8MB
  // d_out phases: Qr bf16 scratch (proj1->proj2), KV fp32 partials (kv->reduce), final out
  ushort_t* QR   = (ushort_t*)d_out;
  float*    KVP  = (float*)d_out;               // [16][1024][1024] fp32 = 64MB

  wtrans4<<<dim3(32, 32, 4), dim3(32, 8), 0, stream>>>(wqr, wk, wqi, wv,
                                                       WtQR, WtK, WtQI, WtV);
  xconvert<<<16384, 256, 0, stream>>>(xr, xi, Xrb, Xib);
  proj_gemm<false><<<dim3(16, 128), 256, 0, stream>>>(Xrb, WtQR, QR, KT, nullptr);
  proj_gemm<true><<<dim3(16, 128), 256, 0, stream>>>(Xib, WtQI, Q, VT, QR);
  kv_gemm<<<dim3(8, 8, 16), 256, 0, stream>>>(VT, KT, KVP);
  kv_reduce<<<4096, 256, 0, stream>>>(KVP, KVT);
  fin_gemm<<<dim3(8, 128), 256, 0, stream>>>(Q, KVT, (float*)d_out);
}

// Round 3
// 439.337 us; speedup vs baseline: 1.5946x; 1.1499x over previous
//
#include <hip/hip_runtime.h>
#include <stdint.h>

typedef unsigned short ushort_t;
typedef __attribute__((ext_vector_type(8))) short bf16x8;   // 8 bf16 = 4 VGPRs
typedef __attribute__((ext_vector_type(4))) float f32x4;

__device__ __forceinline__ ushort_t f2bf(float f) {
  union { float f; uint32_t u; } v; v.f = f;
  uint32_t u = v.u;
  u += 0x7FFFu + ((u >> 16) & 1u);   // RNE
  return (ushort_t)(u >> 16);
}
__device__ __forceinline__ float bf2f(ushort_t h) {
  union { uint32_t u; float f; } v; v.u = ((uint32_t)h) << 16;
  return v.f;
}
__device__ __forceinline__ void gl2lds16(const void* g, void* l) {
  __builtin_amdgcn_global_load_lds(
      (__attribute__((address_space(1))) void*)(uintptr_t)g,
      (__attribute__((address_space(3))) void*)(uint32_t)(uintptr_t)l,
      16, 0, 0);
}

// ---- 128x128 tile, BK=64 bf16 GEMM main loop (C = A * Bt^T) ----
// LDS layout per operand: [row][kg_phys] where kg_phys = kg ^ (row&7), 16B chunks.
// -> fragment ds_read_b128: each 16-lane phase covers each bank-group exactly 2x
//    (2-way aliasing is free, m136). Staging slots are wave-uniform-base + lane*16
//    as global_load_lds requires; the per-lane GLOBAL address is chosen so the
//    right logical element lands in the swizzled slot.
__device__ __forceinline__ void gemm_loop(
    const ushort_t* __restrict__ A, int lda,
    const ushort_t* __restrict__ Bt, int ldb,
    int m0, int n0, int K,
    ushort_t* __restrict__ As, ushort_t* __restrict__ Bs,
    f32x4 (&acc)[4][4]) {
  const int t = threadIdx.x;
  const int lane = t & 63, wid = t >> 6;
  const int wm = wid & 1, wn = wid >> 1;
  const int lr = lane & 15, lq = lane >> 4;

  // staging: 4 slots per thread per operand; slot = i*256 + t (16B each)
  const ushort_t* ap[4];
  const ushort_t* bp[4];
  int dst[4];
  #pragma unroll
  for (int i = 0; i < 4; ++i) {
    int slot = i * 256 + t;
    int row = slot >> 3, kgp = slot & 7;
    int kg = kgp ^ (row & 7);            // logical kgroup held by this slot
    dst[i] = slot * 16;
    ap[i] = A + (size_t)(m0 + row) * lda + kg * 8;
    bp[i] = Bt + (size_t)(n0 + row) * ldb + kg * 8;
  }

  // fragment LDS byte offsets: row*128 + (kg ^ (row&7))*16, kg = s*4 + lq
  int aoff[2][4], boff[2][4];
  #pragma unroll
  for (int s = 0; s < 2; ++s)
    #pragma unroll
    for (int i = 0; i < 4; ++i) {
      int ra = wm * 64 + i * 16 + lr;
      aoff[s][i] = ra * 128 + (((s * 4 + lq) ^ (ra & 7)) * 16);
      int rb = wn * 64 + i * 16 + lr;
      boff[s][i] = rb * 128 + (((s * 4 + lq) ^ (rb & 7)) * 16);
    }

  for (int k0 = 0; k0 < K; k0 += 64) {
    #pragma unroll
    for (int i = 0; i < 4; ++i) gl2lds16(bp[i] + k0, (char*)Bs + dst[i]);
    #pragma unroll
    for (int i = 0; i < 4; ++i) gl2lds16(ap[i] + k0, (char*)As + dst[i]);
    __syncthreads();
    #pragma unroll
    for (int s = 0; s < 2; ++s) {
      bf16x8 af[4], bfr[4];
      #pragma unroll
      for (int i = 0; i < 4; ++i) af[i] = *(const bf16x8*)((const char*)As + aoff[s][i]);
      #pragma unroll
      for (int i = 0; i < 4; ++i) bfr[i] = *(const bf16x8*)((const char*)Bs + boff[s][i]);
      #pragma unroll
      for (int mi = 0; mi < 4; ++mi)
        #pragma unroll
        for (int ni = 0; ni < 4; ++ni)
          acc[mi][ni] = __builtin_amdgcn_mfma_f32_16x16x32_bf16(af[mi], bfr[ni], acc[mi][ni], 0, 0, 0);
    }
    __syncthreads();
  }
}

// ---- fused projection: X[16384][1024] @ Wt[2048][1024]^T, 1D grid 2048 ----
// XCD remap: xcd=bid&7 owns m-slab [xcd*16, xcd*16+16) m-tiles (4MB A = its L2);
// n sweeps fastest so each A-tile is L2-resident across its 16 n-blocks.
template <bool GATE>
__global__ __launch_bounds__(256) void proj_gemm(
    const ushort_t* __restrict__ X, const ushort_t* __restrict__ Wt,
    ushort_t* __restrict__ Cq, ushort_t* __restrict__ Ct,
    const ushort_t* __restrict__ gate) {
  __shared__ ushort_t As[128 * 64];
  __shared__ ushort_t Bs[128 * 64];
  const int bid = blockIdx.x;
  const int xcd = bid & 7, i = bid >> 3;          // i in [0,256)
  const int m0 = (xcd * 16 + (i >> 4)) * 128;
  const int n0 = (i & 15) * 128;
  f32x4 acc[4][4] = {};
  gemm_loop(X, 1024, Wt, 1024, m0, n0, 1024, As, Bs, acc);

  const int t = threadIdx.x, lane = t & 63, wid = t >> 6;
  const int wm = wid & 1, wn = wid >> 1;
  const int lr = lane & 15, lq = lane >> 4;

  if (n0 < 1024) {
    #pragma unroll
    for (int mi = 0; mi < 4; ++mi) {
      int rbase = m0 + wm * 64 + mi * 16 + lq * 4;
      #pragma unroll
      for (int ni = 0; ni < 4; ++ni) {
        int c = n0 + wn * 64 + ni * 16 + lr;
        #pragma unroll
        for (int r = 0; r < 4; ++r) {
          float v = acc[mi][ni][r];
          if constexpr (GATE) v *= bf2f(gate[(size_t)(rbase + r) * 1024 + c]);
          Cq[(size_t)(rbase + r) * 1024 + c] = f2bf(v);
        }
      }
    }
  } else {
    #pragma unroll
    for (int mi = 0; mi < 4; ++mi) {
      int m = m0 + wm * 64 + mi * 16 + lq * 4;
      int b = m >> 12, nseq = m & 4095;
      #pragma unroll
      for (int ni = 0; ni < 4; ++ni) {
        int d = n0 - 1024 + wn * 64 + ni * 16 + lr;
        ushort4 u = make_ushort4(f2bf(acc[mi][ni][0]), f2bf(acc[mi][ni][1]),
                                 f2bf(acc[mi][ni][2]), f2bf(acc[mi][ni][3]));
        *(ushort4*)&Ct[((size_t)(b * 1024 + d) << 12) + nseq] = u;
      }
    }
  }
}

// ---- split-K KV, 1D grid 1024: each XCD owns 2 z-slices (A+B = 4MB = L2) ----
__global__ __launch_bounds__(256) void kv_gemm(
    const ushort_t* __restrict__ VT, const ushort_t* __restrict__ KT,
    float* __restrict__ P) {
  __shared__ ushort_t As[128 * 64];
  __shared__ ushort_t Bs[128 * 64];
  const int bid = blockIdx.x;
  const int xcd = bid & 7, i = bid >> 3;          // i in [0,128)
  const int z = xcd * 2 + (i >> 6);               // 16 z-slices
  const int mn = i & 63;
  const int m0 = (mn >> 3) * 128, n0 = (mn & 7) * 128;
  const int b = z & 3, s = z >> 2;
  const ushort_t* A = VT + ((size_t)b << 22) + s * 1024;
  const ushort_t* Bt = KT + ((size_t)b << 22) + s * 1024;
  f32x4 acc[4][4] = {};
  gemm_loop(A, 4096, Bt, 4096, m0, n0, 1024, As, Bs, acc);

  const int t = threadIdx.x, lane = t & 63, wid = t >> 6;
  const int wm = wid & 1, wn = wid >> 1;
  const int lr = lane & 15, lq = lane >> 4;
  float* C = P + ((size_t)z << 20);
  #pragma unroll
  for (int mi = 0; mi < 4; ++mi) {
    int rbase = m0 + wm * 64 + mi * 16 + lq * 4;
    #pragma unroll
    for (int ni = 0; ni < 4; ++ni) {
      int c = n0 + wn * 64 + ni * 16 + lr;
      #pragma unroll
      for (int r = 0; r < 4; ++r)
        C[(size_t)(rbase + r) * 1024 + c] = acc[mi][ni][r];
    }
  }
}

__global__ __launch_bounds__(256) void kv_reduce(const float* __restrict__ P,
                                                 ushort_t* __restrict__ KVT) {
  size_t e4 = ((size_t)blockIdx.x * 256 + threadIdx.x) * 4;  // < 4M
  int b = (int)(e4 >> 20);
  size_t j = e4 & ((1u << 20) - 1);
  float4 s = make_float4(0.f, 0.f, 0.f, 0.f);
  #pragma unroll
  for (int sp = 0; sp < 4; ++sp) {
    float4 v = *(const float4*)(P + ((size_t)(sp * 4 + b) << 20) + j);
    s.x += v.x; s.y += v.y; s.z += v.z; s.w += v.w;
  }
  *(ushort4*)&KVT[e4] = make_ushort4(f2bf(s.x), f2bf(s.y), f2bf(s.z), f2bf(s.w));
}

// ---- final: Out[m][e] = sum_d Q[m][d] * KVT[b(m)][e][d], 1D grid 1024 ----
__global__ __launch_bounds__(256) void fin_gemm(
    const ushort_t* __restrict__ Q, const ushort_t* __restrict__ KVT,
    float* __restrict__ Out) {
  __shared__ ushort_t As[128 * 64];
  __shared__ ushort_t Bs[128 * 64];
  const int bid = blockIdx.x;
  const int xcd = bid & 7, i = bid >> 3;          // i in [0,128)
  const int m0 = (xcd * 16 + (i >> 3)) * 128;
  const int n0 = (i & 7) * 128;
  const int b = m0 >> 12;
  f32x4 acc[4][4] = {};
  gemm_loop(Q, 1024, KVT + ((size_t)b << 20), 1024, m0, n0, 1024, As, Bs, acc);

  const int t = threadIdx.x, lane = t & 63, wid = t >> 6;
  const int wm = wid & 1, wn = wid >> 1;
  const int lr = lane & 15, lq = lane >> 4;
  #pragma unroll
  for (int mi = 0; mi < 4; ++mi) {
    int rbase = m0 + wm * 64 + mi * 16 + lq * 4;
    #pragma unroll
    for (int ni = 0; ni < 4; ++ni) {
      int c = n0 + wn * 64 + ni * 16 + lr;
      #pragma unroll
      for (int r = 0; r < 4; ++r)
        Out[(size_t)(rbase + r) * 1024 + c] = acc[mi][ni][r];
    }
  }
}

// ---- weight transpose+convert, all four in one launch (z selects) ----
__global__ __launch_bounds__(256) void wtrans4(
    const float* w0, const float* w1, const float* w2, const float* w3,
    ushort_t* o0, ushort_t* o1, ushort_t* o2, ushort_t* o3) {
  __shared__ float tile[32][33];
  const float* W; ushort_t* O;
  switch (blockIdx.z) {
    case 0: W = w0; O = o0; break;
    case 1: W = w1; O = o1; break;
    case 2: W = w2; O = o2; break;
    default: W = w3; O = o3; break;
  }
  const int tx = threadIdx.x, ty = threadIdx.y;   // (32, 8)
  const int bx = blockIdx.x * 32, by = blockIdx.y * 32;
  #pragma unroll
  for (int k = 0; k < 32; k += 8)
    tile[ty + k][tx] = W[(size_t)(by + ty + k) * 1024 + bx + tx];
  __syncthreads();
  #pragma unroll
  for (int k = 0; k < 32; k += 8)
    O[(size_t)(bx + ty + k) * 1024 + by + tx] = f2bf(tile[tx][ty + k]);
}

// ---- X fp32 -> bf16, both tensors in one launch ----
__global__ __launch_bounds__(256) void xconvert(
    const float* __restrict__ xr, const float* __restrict__ xi,
    ushort_t* __restrict__ xrb, ushort_t* __restrict__ xib) {
  const size_t T = 16u * 1024u * 1024u;
  size_t e = ((size_t)blockIdx.x * 256 + threadIdx.x) * 8;
  const float* src; ushort_t* dst;
  if (e < T) { src = xr + e; dst = xrb + e; }
  else       { src = xi + (e - T); dst = xib + (e - T); }
  float4 f0 = *(const float4*)src;
  float4 f1 = *(const float4*)(src + 4);
  ushort4 u0 = make_ushort4(f2bf(f0.x), f2bf(f0.y), f2bf(f0.z), f2bf(f0.w));
  ushort4 u1 = make_ushort4(f2bf(f1.x), f2bf(f1.y), f2bf(f1.z), f2bf(f1.w));
  *(ushort4*)dst = u0;
  *(ushort4*)(dst + 4) = u1;
}

extern "C" void kernel_launch(void* const* d_in, const int* in_sizes, int n_in,
                              void* d_out, int out_size, void* d_ws, size_t ws_size,
                              hipStream_t stream) {
  const float* xr  = (const float*)d_in[0];
  const float* xi  = (const float*)d_in[1];
  const float* wqr = (const float*)d_in[2];
  const float* wqi = (const float*)d_in[3];
  const float* wk  = (const float*)d_in[4];
  const float* wv  = (const float*)d_in[5];

  char* ws = (char*)d_ws;
  const size_t MB = 1024ull * 1024ull;
  ushort_t* WtQR = (ushort_t*)(ws + 0 * MB);    // [WtQR;WtK] contiguous [2048][1024]
  ushort_t* WtK  = (ushort_t*)(ws + 2 * MB);
  ushort_t* WtQI = (ushort_t*)(ws + 4 * MB);    // [WtQI;WtV] contiguous
  ushort_t* WtV  = (ushort_t*)(ws + 6 * MB);
  ushort_t* Xrb  = (ushort_t*)(ws + 8 * MB);    // 32MB; dead after proj1 -> VT overlays
  ushort_t* Xib  = (ushort_t*)(ws + 40 * MB);   // 32MB; dead after proj2 -> KVT overlays
  ushort_t* KT   = (ushort_t*)(ws + 72 * MB);   // 32MB [4][1024][4096]
  ushort_t* Q    = (ushort_t*)(ws + 104 * MB);  // 32MB
  ushort_t* VT   = (ushort_t*)(ws + 8 * MB);    // overlay on Xrb
  ushort_t* KVT  = (ushort_t*)(ws + 40 * MB);   // overlay on Xib, 8MB
  ushort_t* QR   = (ushort_t*)d_out;            // bf16 scratch phase
  float*    KVP  = (float*)d_out;               // [16][1024][1024] fp32 = 64MB phase

  wtrans4<<<dim3(32, 32, 4), dim3(32, 8), 0, stream>>>(wqr, wk, wqi, wv,
                                                       WtQR, WtK, WtQI, WtV);
  xconvert<<<16384, 256, 0, stream>>>(xr, xi, Xrb, Xib);
  proj_gemm<false><<<2048, 256, 0, stream>>>(Xrb, WtQR, QR, KT, nullptr);
  proj_gemm<true><<<2048, 256, 0, stream>>>(Xib, WtQI, Q, VT, QR);
  kv_gemm<<<1024, 256, 0, stream>>>(VT, KT, KVP);
  kv_reduce<<<4096, 256, 0, stream>>>(KVP, KVT);
  fin_gemm<<<1024, 256, 0, stream>>>(Q, KVT, (float*)d_out);
}

// Round 4
// 429.046 us; speedup vs baseline: 1.6328x; 1.0240x over previous
//
#include <hip/hip_runtime.h>
#include <stdint.h>

typedef unsigned short ushort_t;
typedef __attribute__((ext_vector_type(8))) short bf16x8;   // 8 bf16 = 4 VGPRs
typedef __attribute__((ext_vector_type(4))) float f32x4;

__device__ __forceinline__ ushort_t f2bf(float f) {
  union { float f; uint32_t u; } v; v.f = f;
  uint32_t u = v.u;
  u += 0x7FFFu + ((u >> 16) & 1u);   // RNE
  return (ushort_t)(u >> 16);
}
__device__ __forceinline__ float bf2f(ushort_t h) {
  union { uint32_t u; float f; } v; v.u = ((uint32_t)h) << 16;
  return v.f;
}
__device__ __forceinline__ void gl2lds16(const void* g, void* l) {
  __builtin_amdgcn_global_load_lds(
      (__attribute__((address_space(1))) void*)(uintptr_t)g,
      (__attribute__((address_space(3))) void*)(uint32_t)(uintptr_t)l,
      16, 0, 0);
}

// ---- 128x128 tile, BK=64 bf16 GEMM main loop (C = A * Bt^T) ----
// LDS layout per operand: [row][kg_phys], kg_phys = kg ^ (row&7), 16B chunks.
// Fragment ds_read_b128: each 16-lane phase covers each bank-group 2x (free).
__device__ __forceinline__ void gemm_loop(
    const ushort_t* __restrict__ A, int lda,
    const ushort_t* __restrict__ Bt, int ldb,
    int m0, int n0, int K,
    ushort_t* __restrict__ As, ushort_t* __restrict__ Bs,
    f32x4 (&acc)[4][4]) {
  const int t = threadIdx.x;
  const int lane = t & 63, wid = t >> 6;
  const int wm = wid & 1, wn = wid >> 1;
  const int lr = lane & 15, lq = lane >> 4;

  const ushort_t* ap[4];
  const ushort_t* bp[4];
  int dst[4];
  #pragma unroll
  for (int i = 0; i < 4; ++i) {
    int slot = i * 256 + t;
    int row = slot >> 3, kgp = slot & 7;
    int kg = kgp ^ (row & 7);
    dst[i] = slot * 16;
    ap[i] = A + (size_t)(m0 + row) * lda + kg * 8;
    bp[i] = Bt + (size_t)(n0 + row) * ldb + kg * 8;
  }

  int aoff[2][4], boff[2][4];
  #pragma unroll
  for (int s = 0; s < 2; ++s)
    #pragma unroll
    for (int i = 0; i < 4; ++i) {
      int ra = wm * 64 + i * 16 + lr;
      aoff[s][i] = ra * 128 + (((s * 4 + lq) ^ (ra & 7)) * 16);
      int rb = wn * 64 + i * 16 + lr;
      boff[s][i] = rb * 128 + (((s * 4 + lq) ^ (rb & 7)) * 16);
    }

  for (int k0 = 0; k0 < K; k0 += 64) {
    #pragma unroll
    for (int i = 0; i < 4; ++i) gl2lds16(bp[i] + k0, (char*)Bs + dst[i]);
    #pragma unroll
    for (int i = 0; i < 4; ++i) gl2lds16(ap[i] + k0, (char*)As + dst[i]);
    __syncthreads();
    #pragma unroll
    for (int s = 0; s < 2; ++s) {
      bf16x8 af[4], bfr[4];
      #pragma unroll
      for (int i = 0; i < 4; ++i) af[i] = *(const bf16x8*)((const char*)As + aoff[s][i]);
      #pragma unroll
      for (int i = 0; i < 4; ++i) bfr[i] = *(const bf16x8*)((const char*)Bs + boff[s][i]);
      #pragma unroll
      for (int mi = 0; mi < 4; ++mi)
        #pragma unroll
        for (int ni = 0; ni < 4; ++ni)
          acc[mi][ni] = __builtin_amdgcn_mfma_f32_16x16x32_bf16(af[mi], bfr[ni], acc[mi][ni], 0, 0, 0);
    }
    __syncthreads();
  }
}

// ---- fused projection: X[16384][1024] @ Wt[2048][1024]^T, 1D grid 2048 ----
// n0 < 1024  -> Cq bf16 row-major (GATE: multiplied by gate)
// n0 >= 1024 -> K^T/V^T store via LDS-transposed, coalesced full-line writes
template <bool GATE>
__global__ __launch_bounds__(256) void proj_gemm(
    const ushort_t* __restrict__ X, const ushort_t* __restrict__ Wt,
    ushort_t* __restrict__ Cq, ushort_t* __restrict__ Ct,
    const ushort_t* __restrict__ gate) {
  __shared__ ushort_t smem[2 * 128 * 64];       // 32 KB: As | Bs, reused as C-tile
  ushort_t* As = smem;
  ushort_t* Bs = smem + 128 * 64;
  const int bid = blockIdx.x;
  const int xcd = bid & 7, i = bid >> 3;        // XCD owns contiguous m-slab (4MB = L2)
  const int m0 = (xcd * 16 + (i >> 4)) * 128;
  const int n0 = (i & 15) * 128;
  f32x4 acc[4][4] = {};
  gemm_loop(X, 1024, Wt, 1024, m0, n0, 1024, As, Bs, acc);

  const int t = threadIdx.x, lane = t & 63, wid = t >> 6;
  const int wm = wid & 1, wn = wid >> 1;
  const int lr = lane & 15, lq = lane >> 4;

  if (n0 < 1024) {
    #pragma unroll
    for (int mi = 0; mi < 4; ++mi) {
      int rbase = m0 + wm * 64 + mi * 16 + lq * 4;
      #pragma unroll
      for (int ni = 0; ni < 4; ++ni) {
        int c = n0 + wn * 64 + ni * 16 + lr;
        #pragma unroll
        for (int r = 0; r < 4; ++r) {
          float v = acc[mi][ni][r];
          if constexpr (GATE) v *= bf2f(gate[(size_t)(rbase + r) * 1024 + c]);
          Cq[(size_t)(rbase + r) * 1024 + c] = f2bf(v);
        }
      }
    }
  } else {
    // stage C^T (d-major) in LDS; chunk-xor swizzle keeps both sides 2-way max
    #pragma unroll
    for (int mi = 0; mi < 4; ++mi) {
      int ns = wm * 64 + mi * 16 + lq * 4;           // local nseq, 4 consecutive
      int nc = ns >> 3, half = (ns >> 2) & 1;
      #pragma unroll
      for (int ni = 0; ni < 4; ++ni) {
        int dl = wn * 64 + ni * 16 + lr;             // local d
        ushort4 u = make_ushort4(f2bf(acc[mi][ni][0]), f2bf(acc[mi][ni][1]),
                                 f2bf(acc[mi][ni][2]), f2bf(acc[mi][ni][3]));
        *(ushort4*)((char*)smem + dl * 256 + ((nc ^ (dl & 15)) * 16) + half * 8) = u;
      }
    }
    __syncthreads();
    const int b = m0 >> 12, nseq0 = m0 & 4095;
    #pragma unroll
    for (int j = 0; j < 8; ++j) {
      int g = j * 256 + t;
      int dl = g >> 4, nc = g & 15;
      bf16x8 v = *(const bf16x8*)((const char*)smem + dl * 256 + ((nc ^ (dl & 15)) * 16));
      int d = n0 - 1024 + dl;
      *(bf16x8*)&Ct[(((size_t)(b * 1024 + d)) << 12) + nseq0 + nc * 8] = v;
    }
  }
}

// ---- split-K KV, grid 1024: XCD owns 2 z-slices (A+B = 4MB = L2); bf16 partials
__global__ __launch_bounds__(256) void kv_gemm(
    const ushort_t* __restrict__ VT, const ushort_t* __restrict__ KT,
    ushort_t* __restrict__ P) {
  __shared__ ushort_t smem[2 * 128 * 64];
  ushort_t* As = smem;
  ushort_t* Bs = smem + 128 * 64;
  const int bid = blockIdx.x;
  const int xcd = bid & 7, i = bid >> 3;
  const int z = xcd * 2 + (i >> 6);
  const int mn = i & 63;
  const int m0 = (mn >> 3) * 128, n0 = (mn & 7) * 128;
  const int b = z & 3, s = z >> 2;
  const ushort_t* A = VT + ((size_t)b << 22) + s * 1024;
  const ushort_t* Bt = KT + ((size_t)b << 22) + s * 1024;
  f32x4 acc[4][4] = {};
  gemm_loop(A, 4096, Bt, 4096, m0, n0, 1024, As, Bs, acc);

  const int t = threadIdx.x, lane = t & 63, wid = t >> 6;
  const int wm = wid & 1, wn = wid >> 1;
  const int lr = lane & 15, lq = lane >> 4;
  ushort_t* C = P + ((size_t)z << 20);
  #pragma unroll
  for (int mi = 0; mi < 4; ++mi) {
    int rbase = m0 + wm * 64 + mi * 16 + lq * 4;
    #pragma unroll
    for (int ni = 0; ni < 4; ++ni) {
      int c = n0 + wn * 64 + ni * 16 + lr;
      #pragma unroll
      for (int r = 0; r < 4; ++r)
        C[(size_t)(rbase + r) * 1024 + c] = f2bf(acc[mi][ni][r]);
    }
  }
}

__global__ __launch_bounds__(256) void kv_reduce(const ushort_t* __restrict__ P,
                                                 ushort_t* __restrict__ KVT) {
  size_t e4 = ((size_t)blockIdx.x * 256 + threadIdx.x) * 4;  // < 4M
  int b = (int)(e4 >> 20);
  size_t j = e4 & ((1u << 20) - 1);
  float s0 = 0.f, s1 = 0.f, s2 = 0.f, s3 = 0.f;
  #pragma unroll
  for (int sp = 0; sp < 4; ++sp) {
    ushort4 v = *(const ushort4*)(P + ((size_t)(sp * 4 + b) << 20) + j);
    s0 += bf2f(v.x); s1 += bf2f(v.y); s2 += bf2f(v.z); s3 += bf2f(v.w);
  }
  *(ushort4*)&KVT[e4] = make_ushort4(f2bf(s0), f2bf(s1), f2bf(s2), f2bf(s3));
}

// ---- final: Out[m][e] = sum_d Q[m][d] * KVT[b(m)][e][d], fp32 out, grid 1024 ----
__global__ __launch_bounds__(256) void fin_gemm(
    const ushort_t* __restrict__ Q, const ushort_t* __restrict__ KVT,
    float* __restrict__ Out) {
  __shared__ ushort_t smem[2 * 128 * 64];
  ushort_t* As = smem;
  ushort_t* Bs = smem + 128 * 64;
  const int bid = blockIdx.x;
  const int xcd = bid & 7, i = bid >> 3;
  const int m0 = (xcd * 16 + (i >> 3)) * 128;
  const int n0 = (i & 7) * 128;
  const int b = m0 >> 12;
  f32x4 acc[4][4] = {};
  gemm_loop(Q, 1024, KVT + ((size_t)b << 20), 1024, m0, n0, 1024, As, Bs, acc);

  const int t = threadIdx.x, lane = t & 63, wid = t >> 6;
  const int wm = wid & 1, wn = wid >> 1;
  const int lr = lane & 15, lq = lane >> 4;
  #pragma unroll
  for (int mi = 0; mi < 4; ++mi) {
    int rbase = m0 + wm * 64 + mi * 16 + lq * 4;
    #pragma unroll
    for (int ni = 0; ni < 4; ++ni) {
      int c = n0 + wn * 64 + ni * 16 + lr;
      #pragma unroll
      for (int r = 0; r < 4; ++r)
        Out[(size_t)(rbase + r) * 1024 + c] = acc[mi][ni][r];
    }
  }
}

// ---- prep: 4x weight transpose+convert planes, then X fp32->bf16 ----
__global__ __launch_bounds__(256) void prep(
    const float* __restrict__ xr, const float* __restrict__ xi,
    const float* w0, const float* w1, const float* w2, const float* w3,
    ushort_t* __restrict__ xrb, ushort_t* __restrict__ xib,
    ushort_t* o0, ushort_t* o1, ushort_t* o2, ushort_t* o3) {
  const int bid = blockIdx.x;
  const int t = threadIdx.x;
  if (bid < 4096) {
    __shared__ float tile[32][33];
    const float* W; ushort_t* O;
    switch (bid >> 10) {
      case 0: W = w0; O = o0; break;
      case 1: W = w1; O = o1; break;
      case 2: W = w2; O = o2; break;
      default: W = w3; O = o3; break;
    }
    const int within = bid & 1023;
    const int bx = (within & 31) * 32, by = (within >> 5) * 32;
    const int tx = t & 31, ty = t >> 5;   // (32, 8)
    #pragma unroll
    for (int k = 0; k < 32; k += 8)
      tile[ty + k][tx] = W[(size_t)(by + ty + k) * 1024 + bx + tx];
    __syncthreads();
    #pragma unroll
    for (int k = 0; k < 32; k += 8)
      O[(size_t)(bx + ty + k) * 1024 + by + tx] = f2bf(tile[tx][ty + k]);
  } else {
    const size_t T = 16u * 1024u * 1024u;
    size_t e = ((size_t)(bid - 4096) * 256 + t) * 8;
    const float* src; ushort_t* dst;
    if (e < T) { src = xr + e; dst = xrb + e; }
    else       { src = xi + (e - T); dst = xib + (e - T); }
    float4 f0 = *(const float4*)src;
    float4 f1 = *(const float4*)(src + 4);
    ushort4 u0 = make_ushort4(f2bf(f0.x), f2bf(f0.y), f2bf(f0.z), f2bf(f0.w));
    ushort4 u1 = make_ushort4(f2bf(f1.x), f2bf(f1.y), f2bf(f1.z), f2bf(f1.w));
    *(ushort4*)dst = u0;
    *(ushort4*)(dst + 4) = u1;
  }
}

extern "C" void kernel_launch(void* const* d_in, const int* in_sizes, int n_in,
                              void* d_out, int out_size, void* d_ws, size_t ws_size,
                              hipStream_t stream) {
  const float* xr  = (const float*)d_in[0];
  const float* xi  = (const float*)d_in[1];
  const float* wqr = (const float*)d_in[2];
  const float* wqi = (const float*)d_in[3];
  const float* wk  = (const float*)d_in[4];
  const float* wv  = (const float*)d_in[5];

  char* ws = (char*)d_ws;
  const size_t MB = 1024ull * 1024ull;
  ushort_t* WtQR = (ushort_t*)(ws + 0 * MB);    // [WtQR;WtK] contiguous [2048][1024]
  ushort_t* WtK  = (ushort_t*)(ws + 2 * MB);
  ushort_t* WtQI = (ushort_t*)(ws + 4 * MB);    // [WtQI;WtV] contiguous
  ushort_t* WtV  = (ushort_t*)(ws + 6 * MB);
  ushort_t* Xrb  = (ushort_t*)(ws + 8 * MB);    // 32MB; dead after proj1 -> VT overlays
  ushort_t* Xib  = (ushort_t*)(ws + 40 * MB);   // 32MB; dead after proj2 -> KVT overlays
  ushort_t* KT   = (ushort_t*)(ws + 72 * MB);   // 32MB [4][1024][4096]
  ushort_t* Q    = (ushort_t*)(ws + 104 * MB);  // 32MB
  ushort_t* VT   = (ushort_t*)(ws + 8 * MB);    // overlay on Xrb
  ushort_t* KVT  = (ushort_t*)(ws + 40 * MB);   // overlay on Xib, 8MB
  ushort_t* QR   = (ushort_t*)d_out;            // bf16 scratch phase (32MB)
  ushort_t* KVP  = (ushort_t*)d_out;            // [16][1024][1024] bf16 = 32MB phase

  prep<<<20480, 256, 0, stream>>>(xr, xi, wqr, wqi, wk, wv,
                                  Xrb, Xib, WtQR, WtQI, WtK, WtV);
  proj_gemm<false><<<2048, 256, 0, stream>>>(Xrb, WtQR, QR, KT, nullptr);
  proj_gemm<true><<<2048, 256, 0, stream>>>(Xib, WtQI, Q, VT, QR);
  kv_gemm<<<1024, 256, 0, stream>>>(VT, KT, KVP);
  kv_reduce<<<4096, 256, 0, stream>>>(KVP, KVT);
  fin_gemm<<<1024, 256, 0, stream>>>(Q, KVT, (float*)d_out);
}